// Round 8
// baseline (171.893 us; speedup 1.0000x reference)
//
#include <hip/hip_runtime.h>
#include <hip/hip_bf16.h>

#define L_LEN 16384
#define C_CH  256
#define H_HEADS 16
#define W_WIN 15

typedef __attribute__((ext_vector_type(8))) short bf16x8;
typedef __attribute__((ext_vector_type(4))) float f32x4;
typedef unsigned short ushort_t;

// ---------------- ws layout (bytes) ----------------
// Ag     : [256][4096] bf16, per-128B-window XOR-swizzled  @ 0      (2 MB)
// xb     : [16384][256] bf16, per-row XOR-swizzled         @ 2 MB   (8 MB)
// scores : [16][16384] f32 (raw conv out)                  @ 10 MB  (1 MB)
// awf    : [15][8][64][8] bf16 A-fragments of w_heads      @ 11 MB  (120 KB)
// Z      : [16] f32 (softmax denom, atomic)  @ 11M+128K
// bias   : [256] f32                         @ +1024

__device__ __forceinline__ void gll16(const void* g, void* l) {
    __builtin_amdgcn_global_load_lds(
        (const __attribute__((address_space(1))) void*)g,
        (__attribute__((address_space(3))) void*)l, 16, 0, 0);
}

__device__ __forceinline__ ushort_t f2bf(float f) {
    __hip_bfloat16 b = __float2bfloat16(f);
    return *(ushort_t*)&b;
}

// Fused prep: [0,1024) transpose x->xb_swz; [1024,1536) w_tr->Ag_swz;
// [1536,1776) w_heads->awf; 1776: bias-sum + Z zero.
__global__ __launch_bounds__(256) void k_prep(const float* __restrict__ x,
                                              const float* __restrict__ wtr,
                                              const float* __restrict__ wh,
                                              const float* __restrict__ btr,
                                              ushort_t* __restrict__ xb,
                                              ushort_t* __restrict__ Ag,
                                              ushort_t* __restrict__ awf,
                                              float* __restrict__ bias,
                                              float* __restrict__ Z) {
    int bid = blockIdx.x;
    int t = threadIdx.x;
    if (bid < 1024) {
        __shared__ float tile[64][65];
        int l0 = (bid & 255) * 64;
        int c0 = (bid >> 8) * 64;
#pragma unroll
        for (int r = 0; r < 16; ++r) {
            int c = r * 4 + (t >> 6);
            int l = t & 63;
            tile[c][l] = x[(size_t)(c0 + c) * L_LEN + l0 + l];
        }
        __syncthreads();
        int l = t >> 2;
        int cq = (t & 3) * 16;
        ushort_t tmp[16];
#pragma unroll
        for (int i = 0; i < 16; ++i) tmp[i] = f2bf(tile[cq + i][l]);
        char* rowp = (char*)(xb + (size_t)(l0 + l) * C_CH);
        int swz = (l & 7) << 4;
        int b0 = (c0 + cq) * 2;
        *(uint4*)(rowp + (b0 ^ swz)) = *(uint4*)&tmp[0];
        *(uint4*)(rowp + ((b0 + 16) ^ swz)) = *(uint4*)&tmp[8];
    } else if (bid < 1536) {
        int tid = (bid - 1024) * 256 + t;
        size_t D = (size_t)tid * 16;
        int m = (int)(D >> 13);
        int inner = (int)(D & 8191);
        int kt = inner >> 7, wb = inner & 127;
        int ob = kt * 128 + (wb ^ ((m & 7) << 4));
        int k0 = ob >> 1;
        int h = k0 >> 8, c = k0 & 255;
        const float* src = wtr + ((size_t)h * C_CH + m) * C_CH + c;
        ushort_t tmp[8];
#pragma unroll
        for (int i = 0; i < 8; ++i) tmp[i] = f2bf(src[i]);
        *(uint4*)((char*)Ag + D) = *(uint4*)tmp;
    } else if (bid < 1776) {
        int tid = (bid - 1536) * 256 + t;
        int e = tid & 7;
        int lane = (tid >> 3) & 63;
        int ktw = tid >> 9;
        int w = ktw >> 3, kt = ktw & 7;
        int h = lane & 15;
        int c = kt * 32 + (lane >> 4) * 8 + e;
        awf[tid] = f2bf(wh[((size_t)h * C_CH + c) * W_WIN + w]);
    } else {
        float s = 0.f;
#pragma unroll
        for (int h = 0; h < H_HEADS; ++h) s += btr[h * C_CH + t];
        bias[t] = s;
        if (t < H_HEADS) Z[t] = 0.f;
    }
}

// conv via MFMA -> scores[16][L] + per-head expsum partials into Z (atomic).
// grid 512 (l-tile 32), 128 thr (2 waves).
__global__ __launch_bounds__(128) void k_convm(const ushort_t* __restrict__ xb,
                                               const ushort_t* __restrict__ awf,
                                               float* __restrict__ scores,
                                               float* __restrict__ Z) {
    __shared__ char xs[48 * 512];
    int t = threadIdx.x;
    int n0 = blockIdx.x * 32;
#pragma unroll
    for (int i = 0; i < 12; ++i) {
        int chunk = t + i * 128;
        int rr = chunk >> 5;
        int cb = (chunk & 31) * 16;
        int l = n0 - 8 + rr;
        int lc = l < 0 ? 0 : (l >= L_LEN ? L_LEN - 1 : l);
        gll16((const char*)xb + (size_t)lc * 512 + cb, xs + chunk * 16);
    }
    __syncthreads();
    if (n0 == 0 || n0 == L_LEN - 32) {
        int rbase = (n0 == 0) ? 0 : 40;
        uint4 z = {0u, 0u, 0u, 0u};
#pragma unroll
        for (int i = 0; i < 2; ++i) {
            int ch = t + i * 128;
            *(uint4*)(xs + rbase * 512 + ch * 16) = z;
        }
        __syncthreads();
    }
    int wv = t >> 6, lane = t & 63;
    int r = lane & 15, q = lane >> 4;
    const f32x4 vzero = {0.f, 0.f, 0.f, 0.f};
    f32x4 acc[4] = {vzero, vzero, vzero, vzero};
    for (int w = 0; w < 15; ++w) {
        int rr = wv * 16 + r + w + 1;
        const char* rowp = &xs[rr * 512];
        int sw = (rr & 7) << 4;
#pragma unroll
        for (int kt = 0; kt < 8; ++kt) {
            bf16x8 a = *(const bf16x8*)(awf + (size_t)(((w * 8 + kt) * 64 + lane) * 8));
            bf16x8 b = *(const bf16x8*)(rowp + ((kt * 64 + q * 16) ^ sw));
            acc[kt & 3] = __builtin_amdgcn_mfma_f32_16x16x32_bf16(a, b, acc[kt & 3], 0, 0, 0);
        }
    }
    f32x4 s = acc[0] + acc[1] + acc[2] + acc[3];
    int nb = n0 + wv * 16;
#pragma unroll
    for (int e = 0; e < 4; ++e)
        scores[(size_t)(q * 4 + e) * L_LEN + nb + r] = s[e];
    // per-head expsum partial: sum over the 16 r-lanes of this wave, 4 heads/lane
    f32x4 ez;
#pragma unroll
    for (int e = 0; e < 4; ++e) ez[e] = __expf(s[e]);
#pragma unroll
    for (int o = 1; o <= 8; o <<= 1) {
#pragma unroll
        for (int e = 0; e < 4; ++e) ez[e] += __shfl_xor(ez[e], o);
    }
    if (r == 0) {
#pragma unroll
        for (int e = 0; e < 4; ++e) atomicAdd(&Z[q * 4 + e], ez[e]);
    }
}

// GEMM: out[256][16384]. 512 thr / 8 waves, wave tile 64x32, B-reg cache.
// K=128 super-phases (32 total): 2 A-buffers of 32 KB, stage(T+1) after
// barrier, vmcnt(0) lands a full phase after issue. ftab = exp(s)/Z (no max).
#define BPAN 65536
#define ATS2 32768
#define FT   (BPAN + 2 * ATS2)         // 131072; +8 KB ftab -> 139264

__global__ __launch_bounds__(512, 1) void k_gemm(const ushort_t* __restrict__ Ag,
                                                 const ushort_t* __restrict__ xb,
                                                 const float* __restrict__ scores,
                                                 const float* __restrict__ Z,
                                                 const float* __restrict__ bias,
                                                 float* __restrict__ out) {
    __shared__ char lds[FT + 8192];
    int t = threadIdx.x;
    int w = t >> 6, lane = t & 63;
    int m0 = blockIdx.y * 128, n0 = blockIdx.x * 128;
    int wr = w >> 2, wc = w & 3;
    int r = lane & 15, q = lane >> 4;
    int swz = (r & 7) << 4;

    // ---- prologue: B panel (4096 x 16B chunks, 8/thread, linear gll16) ----
#pragma unroll
    for (int i = 0; i < 8; ++i) {
        int chunk = t + i * 512;
        int row = chunk >> 5, cb = (chunk & 31) * 16;
        gll16((const char*)xb + (size_t)(n0 + row) * 512 + cb, lds + chunk * 16);
    }
    // ---- focus table: ftab[h][nn] = exp(s)/Z_h (2048 f32, 4/thread) ----
    {
        int idx = t * 4;
        int hh = idx >> 7, nn = idx & 127;
        float invZ = 1.0f / Z[hh];
        const float* sp = scores + (size_t)hh * L_LEN + n0 + nn;
        float* ft = (float*)(lds + FT);
#pragma unroll
        for (int e = 0; e < 4; ++e)
            ft[idx + e] = __expf(sp[e]) * invZ;
    }
    const f32x4 vzero = {0.f, 0.f, 0.f, 0.f};
    f32x4 oacc[4][2], hacc[4][2];
#pragma unroll
    for (int i = 0; i < 4; ++i)
#pragma unroll
        for (int j = 0; j < 2; ++j) { oacc[i][j] = vzero; hacc[i][j] = vzero; }

    // B fragment register cache (head-invariant), filled during h=0
    bf16x8 br00_0, br00_1, br01_0, br01_1, br10_0, br10_1, br11_0, br11_1,
           br20_0, br20_1, br21_0, br21_1, br30_0, br30_1, br31_0, br31_1;

    // stage super-tile T (=2 kt, 256 B per A row, 32 KB) into buf
    auto stageT = [&](int buf, int T) {
        int base = (t >> 6) * 4096;
        int loff = (t & 63) * 16;
        char* dst = lds + BPAN + buf * ATS2;
        const char* src = (const char*)Ag + (size_t)T * 256;
#pragma unroll
        for (int j = 0; j < 4; ++j) {
            int lin = base + j * 1024 + loff;
            int row = lin >> 8, col = lin & 255;
            gll16(src + (size_t)(m0 + row) * 8192 + col, dst + lin);
        }
    };

    stageT(0, 0);
    __syncthreads();                   // drains B, ftab, stage(0)

#define BRN(QQ, KK, J) br##QQ##KK##_##J
#define LDB(QQ, KK, J)                                                            \
    BRN(QQ, KK, J) = *(const bf16x8*)(lds + (wc * 32 + (J) * 16 + r) * 512 +      \
                          (((QQ) * 128 + (KK) * 64 + q * 16) ^ swz));
#define LDBN(QQ, KK, J)
#define LDA2(Ab, I, KK, P)                                                        \
    (*(const bf16x8*)((Ab) + (wr * 64 + (I) * 16 + r) * 256 + (P) * 128 +         \
                      (((KK) * 64 + q * 16) ^ swz)))
#define CKP(Ab, P, KK, B0, B1)                                                    \
    {                                                                             \
        bf16x8 a0 = LDA2(Ab, 0, KK, P), a1 = LDA2(Ab, 1, KK, P),                  \
               a2 = LDA2(Ab, 2, KK, P), a3 = LDA2(Ab, 3, KK, P);                  \
        hacc[0][0] = __builtin_amdgcn_mfma_f32_16x16x32_bf16(a0, B0, hacc[0][0], 0, 0, 0); \
        hacc[0][1] = __builtin_amdgcn_mfma_f32_16x16x32_bf16(a0, B1, hacc[0][1], 0, 0, 0); \
        hacc[1][0] = __builtin_amdgcn_mfma_f32_16x16x32_bf16(a1, B0, hacc[1][0], 0, 0, 0); \
        hacc[1][1] = __builtin_amdgcn_mfma_f32_16x16x32_bf16(a1, B1, hacc[1][1], 0, 0, 0); \
        hacc[2][0] = __builtin_amdgcn_mfma_f32_16x16x32_bf16(a2, B0, hacc[2][0], 0, 0, 0); \
        hacc[2][1] = __builtin_amdgcn_mfma_f32_16x16x32_bf16(a2, B1, hacc[2][1], 0, 0, 0); \
        hacc[3][0] = __builtin_amdgcn_mfma_f32_16x16x32_bf16(a3, B0, hacc[3][0], 0, 0, 0); \
        hacc[3][1] = __builtin_amdgcn_mfma_f32_16x16x32_bf16(a3, B1, hacc[3][1], 0, 0, 0); \
    }
#define PHASE(BUF, Q0, Q1, LM)                                                    \
    {                                                                             \
        char* Ab = lds + BPAN + (BUF) * ATS2;                                     \
        __builtin_amdgcn_s_setprio(1);                                            \
        LM(Q0, 0, 0) LM(Q0, 0, 1)                                                 \
        CKP(Ab, 0, 0, BRN(Q0, 0, 0), BRN(Q0, 0, 1))                               \
        LM(Q0, 1, 0) LM(Q0, 1, 1)                                                 \
        CKP(Ab, 0, 1, BRN(Q0, 1, 0), BRN(Q0, 1, 1))                               \
        LM(Q1, 0, 0) LM(Q1, 0, 1)                                                 \
        CKP(Ab, 1, 0, BRN(Q1, 0, 0), BRN(Q1, 0, 1))                               \
        LM(Q1, 1, 0) LM(Q1, 1, 1)                                                 \
        CKP(Ab, 1, 1, BRN(Q1, 1, 0), BRN(Q1, 1, 1))                               \
        __builtin_amdgcn_s_setprio(0);                                            \
    }
#define SCALE(H)                                                                  \
    {                                                                             \
        const float* ft = (const float*)(lds + FT) + (H) * 128;                   \
        float f0 = ft[wc * 32 + r], f1 = ft[wc * 32 + 16 + r];                    \
        _Pragma("unroll")                                                         \
        for (int i = 0; i < 4; ++i) {                                             \
            oacc[i][0] += hacc[i][0] * f0;                                        \
            oacc[i][1] += hacc[i][1] * f1;                                        \
            hacc[i][0] = vzero;                                                   \
            hacc[i][1] = vzero;                                                   \
        }                                                                         \
    }
#define WB asm volatile("s_waitcnt vmcnt(0)" ::: "memory"); __builtin_amdgcn_s_barrier();

    // h = 0 (T=0,1): fill B-reg cache while computing
    stageT(1, 1);
    PHASE(0, 0, 1, LDB)
    WB
    stageT(0, 2);
    PHASE(1, 2, 3, LDB)
    SCALE(0);

    for (int h = 1; h < 15; ++h) {
        WB
        stageT(1, 2 * h + 1);
        PHASE(0, 0, 1, LDBN)
        WB
        stageT(0, 2 * h + 2);
        PHASE(1, 2, 3, LDBN)
        SCALE(h);
    }
    // h = 15 (T=30,31)
    WB
    stageT(1, 31);
    PHASE(0, 0, 1, LDBN)
    WB
    PHASE(1, 2, 3, LDBN)
    SCALE(15);

#pragma unroll
    for (int i = 0; i < 4; ++i) {
        int mrow = m0 + wr * 64 + i * 16 + q * 4;
        float4 bv = *(const float4*)&bias[mrow];
        float bvr[4] = {bv.x, bv.y, bv.z, bv.w};
#pragma unroll
        for (int j = 0; j < 2; ++j) {
            int n = n0 + wc * 32 + j * 16 + r;
#pragma unroll
            for (int rr = 0; rr < 4; ++rr)
                out[(size_t)(mrow + rr) * L_LEN + n] = oacc[i][j][rr] + bvr[rr];
        }
    }
#undef WB
#undef SCALE
#undef PHASE
#undef CKP
#undef LDA2
#undef LDBN
#undef LDB
#undef BRN
}

extern "C" void kernel_launch(void* const* d_in, const int* in_sizes, int n_in,
                              void* d_out, int out_size, void* d_ws, size_t ws_size,
                              hipStream_t stream) {
    const float* x   = (const float*)d_in[0];
    const float* wh  = (const float*)d_in[1];
    const float* wtr = (const float*)d_in[3];
    const float* btr = (const float*)d_in[4];
    float* out = (float*)d_out;
    char* ws = (char*)d_ws;

    ushort_t* Ag     = (ushort_t*)(ws);
    ushort_t* xb     = (ushort_t*)(ws + ((size_t)2 << 20));
    float*    scores = (float*)(ws + ((size_t)10 << 20));
    ushort_t* awf    = (ushort_t*)(ws + ((size_t)11 << 20));
    char*     sc     = ws + ((size_t)11 << 20) + (128 << 10);
    float*    Z      = (float*)(sc);
    float*    bias   = (float*)(sc + 1024);

    k_prep<<<dim3(1777), 256, 0, stream>>>(x, wtr, wh, btr, xb, Ag, awf, bias, Z);
    k_convm<<<dim3(512), 128, 0, stream>>>(xb, awf, scores, Z);
    k_gemm<<<dim3(128, 2), 512, 0, stream>>>(Ag, xb, scores, Z, bias, out);
}

// Round 10
// 140.776 us; speedup vs baseline: 1.2210x; 1.2210x over previous
//
#include <hip/hip_runtime.h>
#include <hip/hip_bf16.h>

#define L_LEN 16384
#define C_CH  256
#define H_HEADS 16
#define W_WIN 15

typedef __attribute__((ext_vector_type(8))) short bf16x8;
typedef __attribute__((ext_vector_type(4))) float f32x4;
typedef unsigned short ushort_t;

// ---------------- ws layout (bytes) ----------------
// Ag     : [256][4096] bf16, per-128B-window XOR-swizzled  @ 0      (2 MB)
// xb     : [16384][256] bf16, per-row XOR-swizzled         @ 2 MB   (8 MB)
// scores : [16][16384] f32 (raw conv out)                  @ 10 MB  (1 MB)
// awf    : [15][8][64][8] bf16 A-fragments of w_heads      @ 11 MB  (120 KB)
// Z      : [16][16] f32 (denoms, head h at Z[h*16], 64B-line spaced) @ 11M+128K
// bias   : [256] f32   @ +1024

__device__ __forceinline__ void gll16(const void* g, void* l) {
    __builtin_amdgcn_global_load_lds(
        (const __attribute__((address_space(1))) void*)g,
        (__attribute__((address_space(3))) void*)l, 16, 0, 0);
}

__device__ __forceinline__ ushort_t f2bf(float f) {
    __hip_bfloat16 b = __float2bfloat16(f);
    return *(ushort_t*)&b;
}

// Fused prep: [0,1024) transpose x->xb_swz; [1024,1536) w_tr->Ag_swz;
// [1536,1776) w_heads->awf; 1776: bias-sum + Z zero.
__global__ __launch_bounds__(256) void k_prep(const float* __restrict__ x,
                                              const float* __restrict__ wtr,
                                              const float* __restrict__ wh,
                                              const float* __restrict__ btr,
                                              ushort_t* __restrict__ xb,
                                              ushort_t* __restrict__ Ag,
                                              ushort_t* __restrict__ awf,
                                              float* __restrict__ bias,
                                              float* __restrict__ Z) {
    int bid = blockIdx.x;
    int t = threadIdx.x;
    if (bid < 1024) {
        __shared__ float tile[64][65];
        int l0 = (bid & 255) * 64;
        int c0 = (bid >> 8) * 64;
#pragma unroll
        for (int r = 0; r < 16; ++r) {
            int c = r * 4 + (t >> 6);
            int l = t & 63;
            tile[c][l] = x[(size_t)(c0 + c) * L_LEN + l0 + l];
        }
        __syncthreads();
        int l = t >> 2;
        int cq = (t & 3) * 16;
        ushort_t tmp[16];
#pragma unroll
        for (int i = 0; i < 16; ++i) tmp[i] = f2bf(tile[cq + i][l]);
        char* rowp = (char*)(xb + (size_t)(l0 + l) * C_CH);
        int swz = (l & 7) << 4;
        int b0 = (c0 + cq) * 2;
        *(uint4*)(rowp + (b0 ^ swz)) = *(uint4*)&tmp[0];
        *(uint4*)(rowp + ((b0 + 16) ^ swz)) = *(uint4*)&tmp[8];
    } else if (bid < 1536) {
        int tid = (bid - 1024) * 256 + t;
        size_t D = (size_t)tid * 16;
        int m = (int)(D >> 13);
        int inner = (int)(D & 8191);
        int kt = inner >> 7, wb = inner & 127;
        int ob = kt * 128 + (wb ^ ((m & 7) << 4));
        int k0 = ob >> 1;
        int h = k0 >> 8, c = k0 & 255;
        const float* src = wtr + ((size_t)h * C_CH + m) * C_CH + c;
        ushort_t tmp[8];
#pragma unroll
        for (int i = 0; i < 8; ++i) tmp[i] = f2bf(src[i]);
        *(uint4*)((char*)Ag + D) = *(uint4*)tmp;
    } else if (bid < 1776) {
        int tid = (bid - 1536) * 256 + t;
        int e = tid & 7;
        int lane = (tid >> 3) & 63;
        int ktw = tid >> 9;
        int w = ktw >> 3, kt = ktw & 7;
        int h = lane & 15;
        int c = kt * 32 + (lane >> 4) * 8 + e;
        awf[tid] = f2bf(wh[((size_t)h * C_CH + c) * W_WIN + w]);
    } else {
        float s = 0.f;
#pragma unroll
        for (int h = 0; h < H_HEADS; ++h) s += btr[h * C_CH + t];
        bias[t] = s;
        Z[t] = 0.f;     // zero the whole padded [16][16] block
    }
}

// conv via MFMA -> scores[16][L] + per-head expsum into Z (padded lines).
// grid 256 (l-tile 64), 256 thr (4 waves). awf (120 KB) + x-halo (39.5 KB)
// both LDS-resident -> all inner-loop reads are LDS.
#define CV_XS 122880                     // xs starts after awf copy
__global__ __launch_bounds__(256) void k_convm(const ushort_t* __restrict__ xb,
                                               const ushort_t* __restrict__ awf,
                                               float* __restrict__ scores,
                                               float* __restrict__ Z) {
    __shared__ char sm[CV_XS + 79 * 512];    // 163328 B
    int t = threadIdx.x;
    int n0 = blockIdx.x * 64;
    // stage awf: 7680 x 16B chunks, 30/thread
#pragma unroll
    for (int i = 0; i < 30; ++i) {
        int chunk = t + i * 256;
        gll16((const char*)awf + (size_t)chunk * 16, sm + chunk * 16);
    }
    // stage x halo rows rr in [0,79): l = n0 - 8 + rr (clamped; edges zeroed below)
    for (int i = 0; i < 10; ++i) {
        int chunk = t + i * 256;
        if (chunk < 79 * 32) {
            int rr = chunk >> 5, cb = (chunk & 31) * 16;
            int l = n0 - 8 + rr;
            int lc = l < 0 ? 0 : (l >= L_LEN ? L_LEN - 1 : l);
            gll16((const char*)xb + (size_t)lc * 512 + cb, sm + CV_XS + chunk * 16);
        }
    }
    __syncthreads();
    if (n0 == 0) {                            // rows 0..7 invalid (l<0)
        uint4 zz = {0u, 0u, 0u, 0u};
        *(uint4*)(sm + CV_XS + t * 16) = zz;  // 256*16 = 4096 B = rows 0..7
        __syncthreads();
    } else if (n0 == L_LEN - 64) {            // rows 72..78 invalid (l>=L)
        uint4 zz = {0u, 0u, 0u, 0u};
        if (t < 224) *(uint4*)(sm + CV_XS + 72 * 512 + t * 16) = zz;
        __syncthreads();
    }
    int wv = t >> 6, lane = t & 63;
    int r = lane & 15, q = lane >> 4;
    const f32x4 vzero = {0.f, 0.f, 0.f, 0.f};
    f32x4 acc[4] = {vzero, vzero, vzero, vzero};
    for (int w = 0; w < 15; ++w) {
        int rr = wv * 16 + r + w + 1;
        const char* rowp = sm + CV_XS + rr * 512;
        int sw = (rr & 7) << 4;
#pragma unroll
        for (int kt = 0; kt < 8; ++kt) {
            bf16x8 a = *(const bf16x8*)(sm + ((w * 8 + kt) * 64 + lane) * 16);
            bf16x8 b = *(const bf16x8*)(rowp + ((kt * 64 + q * 16) ^ sw));
            acc[kt & 3] = __builtin_amdgcn_mfma_f32_16x16x32_bf16(a, b, acc[kt & 3], 0, 0, 0);
        }
    }
    f32x4 s = acc[0] + acc[1] + acc[2] + acc[3];
    int nb = n0 + wv * 16;
#pragma unroll
    for (int e = 0; e < 4; ++e)
        scores[(size_t)(q * 4 + e) * L_LEN + nb + r] = s[e];
    // per-head expsum partial over this wave's 16 l's
    f32x4 ez;
#pragma unroll
    for (int e = 0; e < 4; ++e) ez[e] = __expf(s[e]);
#pragma unroll
    for (int o = 1; o <= 8; o <<= 1) {
#pragma unroll
        for (int e = 0; e < 4; ++e) ez[e] += __shfl_xor(ez[e], o);
    }
    if (r == 0) {
#pragma unroll
        for (int e = 0; e < 4; ++e) atomicAdd(&Z[(q * 4 + e) * 16], ez[e]);
    }
}

// GEMM (round-7 schedule): 512 thr / 8 waves, B panel LDS-resident, B-reg
// cache across heads, A through 4 buffers with counted vmcnt(4).
#define BRES 65536
#define ATS  16384
#define FTAB (BRES + 4 * ATS)          // 131072; +8 KB ftab -> 139264 total

__global__ __launch_bounds__(512, 1) void k_gemm(const ushort_t* __restrict__ Ag,
                                                 const ushort_t* __restrict__ xb,
                                                 const float* __restrict__ scores,
                                                 const float* __restrict__ Z,
                                                 const float* __restrict__ bias,
                                                 float* __restrict__ out) {
    __shared__ char lds[FTAB + 8192];
    int t = threadIdx.x;
    int w = t >> 6, lane = t & 63;
    int m0 = blockIdx.y * 128, n0 = blockIdx.x * 128;
    int wr = w >> 2, wc = w & 3;
    int r = lane & 15, q = lane >> 4;
    int swz = (r & 7) << 4;

    // ---- prologue: B panel (4096 x 16B chunks, 8/thread, linear gll16) ----
#pragma unroll
    for (int i = 0; i < 8; ++i) {
        int chunk = t + i * 512;
        int row = chunk >> 5, cb = (chunk & 31) * 16;
        gll16((const char*)xb + (size_t)(n0 + row) * 512 + cb, lds + chunk * 16);
    }
    // ---- focus table: ftab[h][nn] = exp(s)/Z_h (2048 f32, 4/thread) ----
    {
        int idx = t * 4;
        int hh = idx >> 7, nn = idx & 127;
        float invZ = 1.0f / Z[hh * 16];
        const float* sp = scores + (size_t)hh * L_LEN + n0 + nn;
        float* ft = (float*)(lds + FTAB);
#pragma unroll
        for (int e = 0; e < 4; ++e)
            ft[idx + e] = __expf(sp[e]) * invZ;
    }
    const f32x4 vzero = {0.f, 0.f, 0.f, 0.f};
    f32x4 oacc[4][2], hacc[4][2];
#pragma unroll
    for (int i = 0; i < 4; ++i)
#pragma unroll
        for (int j = 0; j < 2; ++j) { oacc[i][j] = vzero; hacc[i][j] = vzero; }

    // B fragment register cache (head-invariant), filled during h=0
    bf16x8 br00_0, br00_1, br01_0, br01_1, br10_0, br10_1, br11_0, br11_1,
           br20_0, br20_1, br21_0, br21_1, br30_0, br30_1, br31_0, br31_1;

    __syncthreads();                       // drains B + ftab (vmcnt 0 here)

    auto stageA = [&](int buf, int kt) {   // 2 x gll16 per thread (16 KB total)
        const char* src = (const char*)Ag + (size_t)(m0 + (t >> 3)) * 8192 + kt * 128 + (t & 7) * 16;
        char* dst = lds + BRES + buf * ATS + t * 16;
#pragma unroll
        for (int j = 0; j < 2; ++j)
            gll16(src + (size_t)j * 64 * 8192, dst + j * 8192);
    };

#define BRN(QQ, KK, J) br##QQ##KK##_##J
#define LDB(QQ, KK, J)                                                            \
    BRN(QQ, KK, J) = *(const bf16x8*)(lds + (wc * 32 + (J) * 16 + r) * 512 +      \
                          (((QQ) * 128 + (KK) * 64 + q * 16) ^ swz))
#define LDA_(Ab, I, KK)                                                           \
    (*(const bf16x8*)((Ab) + (wr * 64 + (I) * 16 + r) * 128 +                     \
                      (((KK) * 64 + q * 16) ^ swz)))
#define CK(Ab, KK, B0, B1)                                                        \
    {                                                                             \
        bf16x8 a0 = LDA_(Ab, 0, KK), a1 = LDA_(Ab, 1, KK),                        \
               a2 = LDA_(Ab, 2, KK), a3 = LDA_(Ab, 3, KK);                        \
        hacc[0][0] = __builtin_amdgcn_mfma_f32_16x16x32_bf16(a0, B0, hacc[0][0], 0, 0, 0); \
        hacc[0][1] = __builtin_amdgcn_mfma_f32_16x16x32_bf16(a0, B1, hacc[0][1], 0, 0, 0); \
        hacc[1][0] = __builtin_amdgcn_mfma_f32_16x16x32_bf16(a1, B0, hacc[1][0], 0, 0, 0); \
        hacc[1][1] = __builtin_amdgcn_mfma_f32_16x16x32_bf16(a1, B1, hacc[1][1], 0, 0, 0); \
        hacc[2][0] = __builtin_amdgcn_mfma_f32_16x16x32_bf16(a2, B0, hacc[2][0], 0, 0, 0); \
        hacc[2][1] = __builtin_amdgcn_mfma_f32_16x16x32_bf16(a2, B1, hacc[2][1], 0, 0, 0); \
        hacc[3][0] = __builtin_amdgcn_mfma_f32_16x16x32_bf16(a3, B0, hacc[3][0], 0, 0, 0); \
        hacc[3][1] = __builtin_amdgcn_mfma_f32_16x16x32_bf16(a3, B1, hacc[3][1], 0, 0, 0); \
    }
#define COMPUTE_LD(BUF, QQ)                                                       \
    {                                                                             \
        char* Ab = lds + BRES + (BUF) * ATS;                                      \
        __builtin_amdgcn_s_setprio(1);                                            \
        LDB(QQ, 0, 0); LDB(QQ, 0, 1);                                             \
        CK(Ab, 0, BRN(QQ, 0, 0), BRN(QQ, 0, 1));                                  \
        LDB(QQ, 1, 0); LDB(QQ, 1, 1);                                             \
        CK(Ab, 1, BRN(QQ, 1, 0), BRN(QQ, 1, 1));                                  \
        __builtin_amdgcn_s_setprio(0);                                            \
    }
#define COMPUTE_RE(BUF, QQ)                                                       \
    {                                                                             \
        char* Ab = lds + BRES + (BUF) * ATS;                                      \
        __builtin_amdgcn_s_setprio(1);                                            \
        CK(Ab, 0, BRN(QQ, 0, 0), BRN(QQ, 0, 1));                                  \
        CK(Ab, 1, BRN(QQ, 1, 0), BRN(QQ, 1, 1));                                  \
        __builtin_amdgcn_s_setprio(0);                                            \
    }
#define SCALE(H)                                                                  \
    {                                                                             \
        const float* ft = (const float*)(lds + FTAB) + (H) * 128;                 \
        float f0 = ft[wc * 32 + r], f1 = ft[wc * 32 + 16 + r];                    \
        _Pragma("unroll")                                                         \
        for (int i = 0; i < 4; ++i) {                                             \
            oacc[i][0] += hacc[i][0] * f0;                                        \
            oacc[i][1] += hacc[i][1] * f1;                                        \
            hacc[i][0] = vzero;                                                   \
            hacc[i][1] = vzero;                                                   \
        }                                                                         \
    }
#define PHASE(SBUF, SKT, CBUF, QQ, CMP)                                           \
    asm volatile("s_waitcnt vmcnt(4)" ::: "memory");                              \
    __builtin_amdgcn_s_barrier();                                                 \
    stageA((SBUF), (SKT));                                                        \
    CMP((CBUF), QQ);

    // warm pipeline: stages 0..2 in flight
    stageA(0, 0); stageA(1, 1); stageA(2, 2);

    // h = 0: load B frags to registers while computing
    PHASE(3, 3, 0, 0, COMPUTE_LD)
    PHASE(0, 4, 1, 1, COMPUTE_LD)
    PHASE(1, 5, 2, 2, COMPUTE_LD)
    PHASE(2, 6, 3, 3, COMPUTE_LD)
    SCALE(0);

    for (int h = 1; h < 15; ++h) {
        int k4 = h * 4;
        PHASE(3, k4 + 3, 0, 0, COMPUTE_RE)
        PHASE(0, k4 + 4, 1, 1, COMPUTE_RE)
        PHASE(1, k4 + 5, 2, 2, COMPUTE_RE)
        PHASE(2, k4 + 6, 3, 3, COMPUTE_RE)
        SCALE(h);
    }

    // h = 15 peeled (kt = 60..63)
    asm volatile("s_waitcnt vmcnt(4)" ::: "memory");
    __builtin_amdgcn_s_barrier();
    stageA(3, 63);
    COMPUTE_RE(0, 0);
    asm volatile("s_waitcnt vmcnt(4)" ::: "memory");
    __builtin_amdgcn_s_barrier();
    COMPUTE_RE(1, 1);
    asm volatile("s_waitcnt vmcnt(2)" ::: "memory");
    __builtin_amdgcn_s_barrier();
    COMPUTE_RE(2, 2);
    asm volatile("s_waitcnt vmcnt(0)" ::: "memory");
    __builtin_amdgcn_s_barrier();
    COMPUTE_RE(3, 3);
    SCALE(15);

#pragma unroll
    for (int i = 0; i < 4; ++i) {
        int mrow = m0 + wr * 64 + i * 16 + q * 4;
        float4 bv = *(const float4*)&bias[mrow];
        float bvr[4] = {bv.x, bv.y, bv.z, bv.w};
#pragma unroll
        for (int j = 0; j < 2; ++j) {
            int n = n0 + wc * 32 + j * 16 + r;
#pragma unroll
            for (int rr = 0; rr < 4; ++rr)
                out[(size_t)(mrow + rr) * L_LEN + n] = oacc[i][j][rr] + bvr[rr];
        }
    }
#undef PHASE
#undef SCALE
#undef COMPUTE_RE
#undef COMPUTE_LD
#undef CK
#undef LDA_
#undef LDB
#undef BRN
}

extern "C" void kernel_launch(void* const* d_in, const int* in_sizes, int n_in,
                              void* d_out, int out_size, void* d_ws, size_t ws_size,
                              hipStream_t stream) {
    const float* x   = (const float*)d_in[0];
    const float* wh  = (const float*)d_in[1];
    const float* wtr = (const float*)d_in[3];
    const float* btr = (const float*)d_in[4];
    float* out = (float*)d_out;
    char* ws = (char*)d_ws;

    ushort_t* Ag     = (ushort_t*)(ws);
    ushort_t* xb     = (ushort_t*)(ws + ((size_t)2 << 20));
    float*    scores = (float*)(ws + ((size_t)10 << 20));
    ushort_t* awf    = (ushort_t*)(ws + ((size_t)11 << 20));
    char*     sc     = ws + ((size_t)11 << 20) + (128 << 10);
    float*    Z      = (float*)(sc);
    float*    bias   = (float*)(sc + 1024);

    k_prep<<<dim3(1777), 256, 0, stream>>>(x, wtr, wh, btr, xb, Ag, awf, bias, Z);
    k_convm<<<dim3(256), 256, 0, stream>>>(xb, awf, scores, Z);
    k_gemm<<<dim3(128, 2), 512, 0, stream>>>(Ag, xb, scores, Z, bias, out);
}

// Round 11
// 119.374 us; speedup vs baseline: 1.4400x; 1.1793x over previous
//
#include <hip/hip_runtime.h>
#include <hip/hip_bf16.h>

#define L_LEN 16384
#define C_CH  256
#define H_HEADS 16
#define W_WIN 15

typedef __attribute__((ext_vector_type(8))) short bf16x8;
typedef __attribute__((ext_vector_type(4))) float f32x4;
typedef unsigned short ushort_t;

// ---------------- ws layout (bytes) ----------------
// Ag     : [256][4096] bf16, per-128B-window XOR-swizzled  @ 0      (2 MB)
// xb     : [16384][256] bf16, per-row XOR-swizzled         @ 2 MB   (8 MB)
// scores : [16][16384] f32 (raw conv out, no b_heads)      @ 10 MB  (1 MB)
// awf    : [15][8][64][8] bf16 A-fragments of w_heads      @ 11 MB  (120 KB)
// MZ     : [16] float2   @ 11M+128K
// bias   : [256] f32     @ +1024

__device__ __forceinline__ void gll16(const void* g, void* l) {
    __builtin_amdgcn_global_load_lds(
        (const __attribute__((address_space(1))) void*)g,
        (__attribute__((address_space(3))) void*)l, 16, 0, 0);
}

__device__ __forceinline__ ushort_t f2bf(float f) {
    __hip_bfloat16 b = __float2bfloat16(f);
    return *(ushort_t*)&b;
}

// Fused prep: blocks [0,1024) transpose x->xb_swz; [1024,1536) w_tr->Ag_swz;
// [1536,1776) w_heads->awf. All 256 thr.  (round-7 verbatim)
__global__ __launch_bounds__(256) void k_prep(const float* __restrict__ x,
                                              const float* __restrict__ wtr,
                                              const float* __restrict__ wh,
                                              ushort_t* __restrict__ xb,
                                              ushort_t* __restrict__ Ag,
                                              ushort_t* __restrict__ awf) {
    int bid = blockIdx.x;
    int t = threadIdx.x;
    if (bid < 1024) {
        __shared__ float tile[64][65];
        int l0 = (bid & 255) * 64;
        int c0 = (bid >> 8) * 64;
#pragma unroll
        for (int r = 0; r < 16; ++r) {
            int c = r * 4 + (t >> 6);
            int l = t & 63;
            tile[c][l] = x[(size_t)(c0 + c) * L_LEN + l0 + l];
        }
        __syncthreads();
        int l = t >> 2;
        int cq = (t & 3) * 16;
        ushort_t tmp[16];
#pragma unroll
        for (int i = 0; i < 16; ++i) tmp[i] = f2bf(tile[cq + i][l]);
        char* rowp = (char*)(xb + (size_t)(l0 + l) * C_CH);
        int swz = (l & 7) << 4;
        int b0 = (c0 + cq) * 2;
        *(uint4*)(rowp + (b0 ^ swz)) = *(uint4*)&tmp[0];
        *(uint4*)(rowp + ((b0 + 16) ^ swz)) = *(uint4*)&tmp[8];
    } else if (bid < 1536) {
        int tid = (bid - 1024) * 256 + t;
        size_t D = (size_t)tid * 16;
        int m = (int)(D >> 13);
        int inner = (int)(D & 8191);
        int kt = inner >> 7, wb = inner & 127;
        int ob = kt * 128 + (wb ^ ((m & 7) << 4));
        int k0 = ob >> 1;
        int h = k0 >> 8, c = k0 & 255;
        const float* src = wtr + ((size_t)h * C_CH + m) * C_CH + c;
        ushort_t tmp[8];
#pragma unroll
        for (int i = 0; i < 8; ++i) tmp[i] = f2bf(src[i]);
        *(uint4*)((char*)Ag + D) = *(uint4*)tmp;
    } else {
        int tid = (bid - 1536) * 256 + t;
        int e = tid & 7;
        int lane = (tid >> 3) & 63;
        int ktw = tid >> 9;
        int w = ktw >> 3, kt = ktw & 7;
        int h = lane & 15;
        int c = kt * 32 + (lane >> 4) * 8 + e;
        awf[tid] = f2bf(wh[((size_t)h * C_CH + c) * W_WIN + w]);
    }
}

// conv via MFMA -> scores[16][L]. grid 512 (l-tile 32), 128 thr. (round-7 verbatim)
__global__ __launch_bounds__(128) void k_convm(const ushort_t* __restrict__ xb,
                                               const ushort_t* __restrict__ awf,
                                               float* __restrict__ scores) {
    __shared__ char xs[48 * 512];
    int t = threadIdx.x;
    int n0 = blockIdx.x * 32;
#pragma unroll
    for (int i = 0; i < 12; ++i) {
        int chunk = t + i * 128;
        int rr = chunk >> 5;
        int cb = (chunk & 31) * 16;
        int l = n0 - 8 + rr;
        int lc = l < 0 ? 0 : (l >= L_LEN ? L_LEN - 1 : l);
        gll16((const char*)xb + (size_t)lc * 512 + cb, xs + chunk * 16);
    }
    __syncthreads();
    if (n0 == 0 || n0 == L_LEN - 32) {
        int rbase = (n0 == 0) ? 0 : 40;
        uint4 z = {0u, 0u, 0u, 0u};
#pragma unroll
        for (int i = 0; i < 2; ++i) {
            int ch = t + i * 128;
            *(uint4*)(xs + rbase * 512 + ch * 16) = z;
        }
        __syncthreads();
    }
    int wv = t >> 6, lane = t & 63;
    int r = lane & 15, q = lane >> 4;
    const f32x4 vzero = {0.f, 0.f, 0.f, 0.f};
    f32x4 acc[4] = {vzero, vzero, vzero, vzero};
    for (int w = 0; w < 15; ++w) {
        int rr = wv * 16 + r + w + 1;
        const char* rowp = &xs[rr * 512];
        int sw = (rr & 7) << 4;
#pragma unroll
        for (int kt = 0; kt < 8; ++kt) {
            bf16x8 a = *(const bf16x8*)(awf + (size_t)(((w * 8 + kt) * 64 + lane) * 8));
            bf16x8 b = *(const bf16x8*)(rowp + ((kt * 64 + q * 16) ^ sw));
            acc[kt & 3] = __builtin_amdgcn_mfma_f32_16x16x32_bf16(a, b, acc[kt & 3], 0, 0, 0);
        }
    }
    f32x4 s = acc[0] + acc[1] + acc[2] + acc[3];
    int nb = n0 + wv * 16;
#pragma unroll
    for (int e = 0; e < 4; ++e)
        scores[(size_t)(q * 4 + e) * L_LEN + nb + r] = s[e];
}

// softmax stats (M,1/Z) per head + head-summed bias. grid 17 x 1024. (round-7 verbatim)
__global__ __launch_bounds__(1024) void k_stats(const float* __restrict__ scores,
                                                const float* __restrict__ btr,
                                                float2* __restrict__ MZ,
                                                float* __restrict__ bias) {
    int t = threadIdx.x;
    if (blockIdx.x == 16) {
        if (t < 256) {
            float s = 0.f;
#pragma unroll
            for (int h = 0; h < H_HEADS; ++h) s += btr[h * C_CH + t];
            bias[t] = s;
        }
        return;
    }
    __shared__ float red[17];
    int h = blockIdx.x;
    int wid = t >> 6, ln = t & 63;
    const float* sp = scores + (size_t)h * L_LEN;
    float v[16];
    float mx = -1e30f;
#pragma unroll
    for (int i = 0; i < 16; ++i) {
        v[i] = sp[i * 1024 + t];
        mx = fmaxf(mx, v[i]);
    }
    for (int o = 32; o > 0; o >>= 1) mx = fmaxf(mx, __shfl_xor(mx, o));
    if (ln == 0) red[wid] = mx;
    __syncthreads();
    if (t == 0) {
        float m2 = red[0];
        for (int i = 1; i < 16; ++i) m2 = fmaxf(m2, red[i]);
        red[16] = m2;
    }
    __syncthreads();
    float M = red[16];
    float s = 0.f;
#pragma unroll
    for (int i = 0; i < 16; ++i) s += __expf(v[i] - M);
    for (int o = 32; o > 0; o >>= 1) s += __shfl_xor(s, o);
    __syncthreads();
    if (ln == 0) red[wid] = s;
    __syncthreads();
    if (t == 0) {
        float Z = 0.f;
        for (int i = 0; i < 16; ++i) Z += red[i];
        float2 r; r.x = M; r.y = 1.0f / Z;
        MZ[h] = r;
    }
}

// GEMM: 512 thr / 8 waves retiled 4m x 2n (wave tile 32x64).
// A LDS-read traffic halves vs 2m x 4n (2 waves share A rows, not 4).
// B register cache doubles to 32 frags (64 VGPR), B LDS reads only at h=0.
#define BRES 65536
#define ATS  16384
#define FTAB (BRES + 4 * ATS)          // 131072; +8 KB ftab -> 139264 total

__global__ __launch_bounds__(512, 1) void k_gemm(const ushort_t* __restrict__ Ag,
                                                 const ushort_t* __restrict__ xb,
                                                 const float* __restrict__ scores,
                                                 const float2* __restrict__ MZ,
                                                 const float* __restrict__ bias,
                                                 float* __restrict__ out) {
    __shared__ char lds[FTAB + 8192];
    int t = threadIdx.x;
    int w = t >> 6, lane = t & 63;
    int m0 = blockIdx.y * 128, n0 = blockIdx.x * 128;
    int wr = w >> 1, wc = w & 1;          // 4m x 2n
    int r = lane & 15, q = lane >> 4;
    int swz = (r & 7) << 4;

    // ---- prologue: B panel (4096 x 16B chunks, 8/thread, linear gll16) ----
#pragma unroll
    for (int i = 0; i < 8; ++i) {
        int chunk = t + i * 512;
        int row = chunk >> 5, cb = (chunk & 31) * 16;
        gll16((const char*)xb + (size_t)(n0 + row) * 512 + cb, lds + chunk * 16);
    }
    // ---- focus table: ftab[h][nn] = exp(s - M_h)/Z_h (2048 f32, 4/thread) ----
    {
        int idx = t * 4;
        int hh = idx >> 7, nn = idx & 127;
        float2 mz = MZ[hh];
        const float* sp = scores + (size_t)hh * L_LEN + n0 + nn;
        float* ft = (float*)(lds + FTAB);
#pragma unroll
        for (int e = 0; e < 4; ++e)
            ft[idx + e] = __expf(sp[e] - mz.x) * mz.y;
    }
    const f32x4 vzero = {0.f, 0.f, 0.f, 0.f};
    f32x4 oacc[2][4], hacc[2][4];
#pragma unroll
    for (int i = 0; i < 2; ++i)
#pragma unroll
        for (int j = 0; j < 4; ++j) { oacc[i][j] = vzero; hacc[i][j] = vzero; }

    // B fragment register cache (head-invariant): 32 frags, filled during h=0
    bf16x8 br00_0, br00_1, br00_2, br00_3, br01_0, br01_1, br01_2, br01_3,
           br10_0, br10_1, br10_2, br10_3, br11_0, br11_1, br11_2, br11_3,
           br20_0, br20_1, br20_2, br20_3, br21_0, br21_1, br21_2, br21_3,
           br30_0, br30_1, br30_2, br30_3, br31_0, br31_1, br31_2, br31_3;

    __syncthreads();                       // drains B + ftab (vmcnt 0 here)

    auto stageA = [&](int buf, int kt) {   // 2 x gll16 per thread (16 KB total)
        const char* src = (const char*)Ag + (size_t)(m0 + (t >> 3)) * 8192 + kt * 128 + (t & 7) * 16;
        char* dst = lds + BRES + buf * ATS + t * 16;
#pragma unroll
        for (int j = 0; j < 2; ++j)
            gll16(src + (size_t)j * 64 * 8192, dst + j * 8192);
    };

#define BRN(QQ, KK, J) br##QQ##KK##_##J
#define LDB(QQ, KK, J)                                                            \
    BRN(QQ, KK, J) = *(const bf16x8*)(lds + (wc * 64 + (J) * 16 + r) * 512 +      \
                          (((QQ) * 128 + (KK) * 64 + q * 16) ^ swz));
#define LDA_(Ab, I, KK)                                                           \
    (*(const bf16x8*)((Ab) + (wr * 32 + (I) * 16 + r) * 128 +                     \
                      (((KK) * 64 + q * 16) ^ swz)))
#define CK(Ab, KK, B0, B1, B2, B3)                                                \
    {                                                                             \
        bf16x8 a0 = LDA_(Ab, 0, KK), a1 = LDA_(Ab, 1, KK);                        \
        hacc[0][0] = __builtin_amdgcn_mfma_f32_16x16x32_bf16(a0, B0, hacc[0][0], 0, 0, 0); \
        hacc[0][1] = __builtin_amdgcn_mfma_f32_16x16x32_bf16(a0, B1, hacc[0][1], 0, 0, 0); \
        hacc[0][2] = __builtin_amdgcn_mfma_f32_16x16x32_bf16(a0, B2, hacc[0][2], 0, 0, 0); \
        hacc[0][3] = __builtin_amdgcn_mfma_f32_16x16x32_bf16(a0, B3, hacc[0][3], 0, 0, 0); \
        hacc[1][0] = __builtin_amdgcn_mfma_f32_16x16x32_bf16(a1, B0, hacc[1][0], 0, 0, 0); \
        hacc[1][1] = __builtin_amdgcn_mfma_f32_16x16x32_bf16(a1, B1, hacc[1][1], 0, 0, 0); \
        hacc[1][2] = __builtin_amdgcn_mfma_f32_16x16x32_bf16(a1, B2, hacc[1][2], 0, 0, 0); \
        hacc[1][3] = __builtin_amdgcn_mfma_f32_16x16x32_bf16(a1, B3, hacc[1][3], 0, 0, 0); \
    }
#define COMPUTE_LD(BUF, QQ)                                                       \
    {                                                                             \
        char* Ab = lds + BRES + (BUF) * ATS;                                      \
        __builtin_amdgcn_s_setprio(1);                                            \
        LDB(QQ, 0, 0) LDB(QQ, 0, 1) LDB(QQ, 0, 2) LDB(QQ, 0, 3)                   \
        CK(Ab, 0, BRN(QQ, 0, 0), BRN(QQ, 0, 1), BRN(QQ, 0, 2), BRN(QQ, 0, 3));    \
        LDB(QQ, 1, 0) LDB(QQ, 1, 1) LDB(QQ, 1, 2) LDB(QQ, 1, 3)                   \
        CK(Ab, 1, BRN(QQ, 1, 0), BRN(QQ, 1, 1), BRN(QQ, 1, 2), BRN(QQ, 1, 3));    \
        __builtin_amdgcn_s_setprio(0);                                            \
    }
#define COMPUTE_RE(BUF, QQ)                                                       \
    {                                                                             \
        char* Ab = lds + BRES + (BUF) * ATS;                                      \
        __builtin_amdgcn_s_setprio(1);                                            \
        CK(Ab, 0, BRN(QQ, 0, 0), BRN(QQ, 0, 1), BRN(QQ, 0, 2), BRN(QQ, 0, 3));    \
        CK(Ab, 1, BRN(QQ, 1, 0), BRN(QQ, 1, 1), BRN(QQ, 1, 2), BRN(QQ, 1, 3));    \
        __builtin_amdgcn_s_setprio(0);                                            \
    }
#define SCALE(H)                                                                  \
    {                                                                             \
        const float* ft = (const float*)(lds + FTAB) + (H) * 128;                 \
        float f0 = ft[wc * 64 + r], f1 = ft[wc * 64 + 16 + r];                    \
        float f2 = ft[wc * 64 + 32 + r], f3 = ft[wc * 64 + 48 + r];               \
        _Pragma("unroll")                                                         \
        for (int i = 0; i < 2; ++i) {                                             \
            oacc[i][0] += hacc[i][0] * f0;                                        \
            oacc[i][1] += hacc[i][1] * f1;                                        \
            oacc[i][2] += hacc[i][2] * f2;                                        \
            oacc[i][3] += hacc[i][3] * f3;                                        \
            hacc[i][0] = vzero; hacc[i][1] = vzero;                               \
            hacc[i][2] = vzero; hacc[i][3] = vzero;                               \
        }                                                                         \
    }
#define PHASE(SBUF, SKT, CBUF, QQ, CMP)                                           \
    asm volatile("s_waitcnt vmcnt(4)" ::: "memory");                              \
    __builtin_amdgcn_s_barrier();                                                 \
    stageA((SBUF), (SKT));                                                        \
    CMP((CBUF), QQ);

    // warm pipeline: stages 0..2 in flight
    stageA(0, 0); stageA(1, 1); stageA(2, 2);

    // h = 0: load B frags to registers while computing
    PHASE(3, 3, 0, 0, COMPUTE_LD)
    PHASE(0, 4, 1, 1, COMPUTE_LD)
    PHASE(1, 5, 2, 2, COMPUTE_LD)
    PHASE(2, 6, 3, 3, COMPUTE_LD)
    SCALE(0);

    for (int h = 1; h < 15; ++h) {
        int k4 = h * 4;
        PHASE(3, k4 + 3, 0, 0, COMPUTE_RE)
        PHASE(0, k4 + 4, 1, 1, COMPUTE_RE)
        PHASE(1, k4 + 5, 2, 2, COMPUTE_RE)
        PHASE(2, k4 + 6, 3, 3, COMPUTE_RE)
        SCALE(h);
    }

    // h = 15 peeled (kt = 60..63)
    asm volatile("s_waitcnt vmcnt(4)" ::: "memory");
    __builtin_amdgcn_s_barrier();
    stageA(3, 63);
    COMPUTE_RE(0, 0);
    asm volatile("s_waitcnt vmcnt(4)" ::: "memory");
    __builtin_amdgcn_s_barrier();
    COMPUTE_RE(1, 1);
    asm volatile("s_waitcnt vmcnt(2)" ::: "memory");
    __builtin_amdgcn_s_barrier();
    COMPUTE_RE(2, 2);
    asm volatile("s_waitcnt vmcnt(0)" ::: "memory");
    __builtin_amdgcn_s_barrier();
    COMPUTE_RE(3, 3);
    SCALE(15);

#pragma unroll
    for (int i = 0; i < 2; ++i) {
        int mrow = m0 + wr * 32 + i * 16 + q * 4;
        float4 bv = *(const float4*)&bias[mrow];
        float bvr[4] = {bv.x, bv.y, bv.z, bv.w};
#pragma unroll
        for (int j = 0; j < 4; ++j) {
            int n = n0 + wc * 64 + j * 16 + r;
#pragma unroll
            for (int rr = 0; rr < 4; ++rr)
                out[(size_t)(mrow + rr) * L_LEN + n] = oacc[i][j][rr] + bvr[rr];
        }
    }
#undef PHASE
#undef SCALE
#undef COMPUTE_RE
#undef COMPUTE_LD
#undef CK
#undef LDA_
#undef LDB
#undef BRN
}

extern "C" void kernel_launch(void* const* d_in, const int* in_sizes, int n_in,
                              void* d_out, int out_size, void* d_ws, size_t ws_size,
                              hipStream_t stream) {
    const float* x   = (const float*)d_in[0];
    const float* wh  = (const float*)d_in[1];
    const float* wtr = (const float*)d_in[3];
    const float* btr = (const float*)d_in[4];
    float* out = (float*)d_out;
    char* ws = (char*)d_ws;

    ushort_t* Ag     = (ushort_t*)(ws);
    ushort_t* xb     = (ushort_t*)(ws + ((size_t)2 << 20));
    float*    scores = (float*)(ws + ((size_t)10 << 20));
    ushort_t* awf    = (ushort_t*)(ws + ((size_t)11 << 20));
    char*     sc     = ws + ((size_t)11 << 20) + (128 << 10);
    float2*   MZ     = (float2*)(sc);
    float*    bias   = (float*)(sc + 1024);

    k_prep<<<dim3(1776), 256, 0, stream>>>(x, wtr, wh, xb, Ag, awf);
    k_convm<<<dim3(512), 128, 0, stream>>>(xb, awf, scores);
    k_stats<<<dim3(17), 1024, 0, stream>>>(scores, btr, MZ, bias);
    k_gemm<<<dim3(128, 2), 512, 0, stream>>>(Ag, xb, scores, MZ, bias, out);
}